// Round 4
// baseline (512.834 us; speedup 1.0000x reference)
//
#include <hip/hip_runtime.h>
#include <hip/hip_bf16.h>

#define N_NODES 100000
#define E_EDGES 800000
#define CAP 32            // Poisson(8) max degree over 100k nodes ~ 25; 32 is safe
#define LN_EPS 1e-5f
#define WPAD 264          // 256 + 8 bf16 pad -> max 2-way LDS bank aliasing (free)
#define NSLICE 391        // ceil(N_NODES / 256); 256*391 = 100096
#define SCAN4 200000      // E_EDGES / 4 int4 groups of the dst array
#define CONV_PER_BLOCK 12500   // 3.2M float4 groups of x / 256 blocks

typedef __attribute__((ext_vector_type(4))) float f32x4;
typedef __attribute__((ext_vector_type(8))) short short8;

__device__ __forceinline__ unsigned short f2bf(float f) {
    __hip_bfloat16 h = __float2bfloat16(f);
    return *reinterpret_cast<unsigned short*>(&h);
}
__device__ __forceinline__ float bflo(unsigned int u) { return __uint_as_float(u << 16); }
__device__ __forceinline__ float bfhi(unsigned int u) { return __uint_as_float(u & 0xffff0000u); }

// ---- fill_slice: slice-owned edge counting (LDS atomics only) + x->bf16 ----
// Block b owns nodes [b*NSLICE, b*NSLICE+NSLICE). It scans ALL dst indices
// (3.2MB, L2-resident across the 256 blocks), builds cnt+slot lists in LDS,
// then writes them back fully coalesced. No global atomics, no scattered
// global stores. x conversion is interleaved grid-wide via phase rotation.
__global__ __launch_bounds__(256) void fill_slice(
    const float* __restrict__ x, const int* __restrict__ ei,
    unsigned short* __restrict__ xb, int* __restrict__ cnt,
    int* __restrict__ slots)
{
    __shared__ int cnt_l[NSLICE];
    __shared__ int slots_l[NSLICE * CAP];
    const int t = threadIdx.x, b = blockIdx.x;
    const int base = b * NSLICE;
    for (int i = t; i < NSLICE; i += 256) cnt_l[i] = 0;
    __syncthreads();

    auto do_convert = [&]() {
        const float4* x4 = reinterpret_cast<const float4*>(x);
        ushort4* xb4 = reinterpret_cast<ushort4*>(xb);
        const int j0 = b * CONV_PER_BLOCK;
        for (int j = t; j < CONV_PER_BLOCK; j += 256) {
            float4 v = x4[j0 + j];
            ushort4 o;
            o.x = f2bf(v.x); o.y = f2bf(v.y); o.z = f2bf(v.z); o.w = f2bf(v.w);
            xb4[j0 + j] = o;
        }
    };
    auto do_scan = [&]() {
        const int4* d4 = reinterpret_cast<const int4*>(ei + E_EDGES);
        for (int g = t; g < SCAN4; g += 256) {
            int4 d = d4[g];
#pragma unroll
            for (int k = 0; k < 4; ++k) {
                int dst = (k == 0) ? d.x : (k == 1) ? d.y : (k == 2) ? d.z : d.w;
                unsigned lo = (unsigned)(dst - base);
                if (lo < NSLICE) {
                    int src = ei[4 * g + k];            // L2/L3-served hit load
                    int p = atomicAdd(&cnt_l[lo], 1);   // LDS atomic
                    if (p < CAP) slots_l[lo * CAP + p] = src;
                }
            }
        }
    };
    if (b & 1) { do_convert(); do_scan(); }
    else       { do_scan(); do_convert(); }
    __syncthreads();
    for (int i = t; i < NSLICE; i += 256) cnt[base + i] = cnt_l[i];
    for (int i = t; i < NSLICE * CAP; i += 256) slots[base * CAP + i] = slots_l[i];
}

// ---- quad-row pull-gather mean into bf16 neigh ------------------------------
// Wave per node. Lane = (subi = lane>>4) neighbor sub-index, (chunk = lane&15)
// 16B feature chunk. One uint4 load = 4 neighbor rows (1KB) per instruction.
__global__ __launch_bounds__(256) void gather_kernel(
    const unsigned short* __restrict__ xb, const int* __restrict__ cnt,
    const int* __restrict__ slots, unsigned short* __restrict__ nb)
{
    int node = (blockIdx.x * blockDim.x + threadIdx.x) >> 6;
    int lane = threadIdx.x & 63;
    if (node >= N_NODES) return;
    int c = cnt[node];
    int cc = c > CAP ? CAP : c;
    int myslot = (lane < cc) ? slots[node * CAP + lane] : 0;  // lanes >= cc hold 0
    const int subi = lane >> 4, chunk = lane & 15;
    float acc[8];
#pragma unroll
    for (int k = 0; k < 8; ++k) acc[k] = 0.f;
    const uint4* x4 = reinterpret_cast<const uint4*>(xb);  // 16 uint4 per row
    for (int i = 0; i < cc; i += 4) {
        int idx = i + subi;                 // <= cc+3 <= 35 < 64: safe shfl index
        int s = __shfl(myslot, idx);        // idx >= cc -> lane holds 0 -> row 0
        uint4 v = x4[s * 16 + chunk];
        if (idx < cc) {
            acc[0] += bflo(v.x); acc[1] += bfhi(v.x);
            acc[2] += bflo(v.y); acc[3] += bfhi(v.y);
            acc[4] += bflo(v.z); acc[5] += bfhi(v.z);
            acc[6] += bflo(v.w); acc[7] += bfhi(v.w);
        }
    }
#pragma unroll
    for (int k = 0; k < 8; ++k) {           // sum across the 4 neighbor groups
        acc[k] += __shfl_xor(acc[k], 16);
        acc[k] += __shfl_xor(acc[k], 32);
    }
    if (subi == 0) {
        float inv = 1.0f / (float)(c > 1 ? c : 1);
        uint4 o;
        o.x = ((unsigned)f2bf(acc[1] * inv) << 16) | f2bf(acc[0] * inv);
        o.y = ((unsigned)f2bf(acc[3] * inv) << 16) | f2bf(acc[2] * inv);
        o.z = ((unsigned)f2bf(acc[5] * inv) << 16) | f2bf(acc[4] * inv);
        o.w = ((unsigned)f2bf(acc[7] * inv) << 16) | f2bf(acc[6] * inv);
        reinterpret_cast<uint4*>(nb)[node * 16 + chunk] = o;
    }
}

// ---- MFMA GEMM (K=256 over [x|neigh]) + bias + ReLU + LayerNorm ------------
// Block = 256 thr = 4 waves; wave owns 64 rows x 128 cols.
// A-frag: A[m=lane&15][k=quad*8+j]; C/D: col=lane&15, row=quad*4+reg.
__global__ __launch_bounds__(256, 2) void fused_mfma(
    const unsigned short* __restrict__ xb, const unsigned short* __restrict__ nb,
    const float* __restrict__ Wself, const float* __restrict__ Wneigh,
    const float* __restrict__ bias, const float* __restrict__ gamma,
    const float* __restrict__ beta, float* __restrict__ out)
{
    __shared__ unsigned short WT[128][WPAD];   // [out_col][kk]; kk<128: Ws, else Wn
    const int t = threadIdx.x;
    const float4* Ws4 = reinterpret_cast<const float4*>(Wself);
    const float4* Wn4 = reinterpret_cast<const float4*>(Wneigh);
    for (int idx = t; idx < 4096; idx += 256) {
        int n = idx >> 5, k4 = (idx & 31) << 2;     // W is [n][k], coalesced read
        float4 a = Ws4[idx];
        float4 b = Wn4[idx];
        ushort4 ua, ub;
        ua.x = f2bf(a.x); ua.y = f2bf(a.y); ua.z = f2bf(a.z); ua.w = f2bf(a.w);
        ub.x = f2bf(b.x); ub.y = f2bf(b.y); ub.z = f2bf(b.z); ub.w = f2bf(b.w);
        *reinterpret_cast<ushort4*>(&WT[n][k4]) = ua;
        *reinterpret_cast<ushort4*>(&WT[n][128 + k4]) = ub;
    }
    __syncthreads();

    const int lane = t & 63, wave = t >> 6;
    const int l16 = lane & 15, quad = lane >> 4;
    float bia[8], gam[8], bet[8];
#pragma unroll
    for (int n = 0; n < 8; ++n) {
        int col = n * 16 + l16;
        bia[n] = bias[col]; gam[n] = gamma[col]; bet[n] = beta[col];
    }

    const int ntiles = (N_NODES + 255) / 256;
    for (int tile = blockIdx.x; tile < ntiles; tile += gridDim.x) {
        const int rowbase = tile * 256 + wave * 64;
        f32x4 acc[4][8];
#pragma unroll
        for (int m = 0; m < 4; ++m)
#pragma unroll
            for (int n = 0; n < 8; ++n) acc[m][n] = (f32x4)0.f;
        int rows[4];
#pragma unroll
        for (int m = 0; m < 4; ++m) {
            int r = rowbase + m * 16 + l16;
            rows[m] = r < N_NODES ? r : N_NODES - 1;   // tail clamp; store guarded
        }
#pragma unroll
        for (int kstep = 0; kstep < 8; ++kstep) {
            const unsigned short* Asrc = (kstep < 4) ? xb : nb;
            const int koff = (kstep & 3) * 32 + quad * 8;
            short8 a[4];
#pragma unroll
            for (int m = 0; m < 4; ++m)
                a[m] = *reinterpret_cast<const short8*>(Asrc + rows[m] * 128 + koff);
#pragma unroll
            for (int n = 0; n < 8; ++n) {
                short8 b = *reinterpret_cast<const short8*>(&WT[n * 16 + l16][kstep * 32 + quad * 8]);
#pragma unroll
                for (int m = 0; m < 4; ++m)
                    acc[m][n] = __builtin_amdgcn_mfma_f32_16x16x32_bf16(a[m], b, acc[m][n], 0, 0, 0);
            }
        }
        // epilogue: bias+ReLU+LN; row R's 128 cols live in the 16 lanes of one quad
#pragma unroll
        for (int m = 0; m < 4; ++m) {
#pragma unroll
            for (int r = 0; r < 4; ++r) {
                float h[8], s = 0.f, q = 0.f;
#pragma unroll
                for (int n = 0; n < 8; ++n) {
                    float v = acc[m][n][r] + bia[n];
                    v = fmaxf(v, 0.f);
                    h[n] = v; s += v; q += v * v;
                }
#pragma unroll
                for (int msk = 1; msk <= 8; msk <<= 1) {
                    s += __shfl_xor(s, msk);
                    q += __shfl_xor(q, msk);
                }
                const float mu = s * (1.f / 128.f);
                const float var = q * (1.f / 128.f) - mu * mu;
                const float rs = rsqrtf(var + LN_EPS);
                const int R = rowbase + m * 16 + quad * 4 + r;
                if (R < N_NODES) {
#pragma unroll
                    for (int n = 0; n < 8; ++n)
                        out[R * 128 + n * 16 + l16] = (h[n] - mu) * rs * gam[n] + bet[n];
                }
            }
        }
    }
}

extern "C" void kernel_launch(void* const* d_in, const int* in_sizes, int n_in,
                              void* d_out, int out_size, void* d_ws, size_t ws_size,
                              hipStream_t stream) {
    const float* x      = (const float*)d_in[0];
    const int*   ei     = (const int*)d_in[1];
    const float* Wself  = (const float*)d_in[2];
    const float* Wneigh = (const float*)d_in[3];
    const float* bias   = (const float*)d_in[4];
    const float* gamma  = (const float*)d_in[5];
    const float* beta   = (const float*)d_in[6];
    float* out = (float*)d_out;

    char* ws = (char*)d_ws;
    int* cnt   = (int*)ws;                                   // 100096 ints
    int* slots = (int*)(ws + 400384);                        // 100096*32 ints
    unsigned short* xb  = (unsigned short*)(ws + 13212672);  // 25.6 MB
    unsigned short* nb  = (unsigned short*)(ws + 38812672);  // 25.6 MB

    fill_slice<<<256, 256, 0, stream>>>(x, ei, xb, cnt, slots);
    gather_kernel<<<(N_NODES + 3) / 4, 256, 0, stream>>>(xb, cnt, slots, nb);
    const int ntiles = (N_NODES + 255) / 256;
    fused_mfma<<<ntiles, 256, 0, stream>>>(xb, nb, Wself, Wneigh, bias, gamma, beta, out);
}

// Round 5
// 210.374 us; speedup vs baseline: 2.4377x; 2.4377x over previous
//
#include <hip/hip_runtime.h>
#include <hip/hip_bf16.h>

#define N_NODES 100000
#define E_EDGES 800000
#define CAP 32             // max stored neighbors; P(Poisson(8) > 32) ~ 3e-6 total
#define LN_EPS 1e-5f
#define WPAD 264           // 256 + 8 bf16 pad -> max 2-way LDS bank aliasing (free)
#define NBK 256            // dst buckets = pass-2 blocks
#define NSLICE 391         // nodes per bucket; 256*391 = 100096 >= N
#define BKCAP 4096         // bucket capacity (mean 3125, sd ~56; 17 sigma)
#define EPB 3125           // edges per pass-1 partition block (800000/256)
#define MAGIC391 10984572ULL   // ceil(2^32/391); exact div for dst < 100096
#define CONV_PER_BLOCK 12500   // 3.2M float4 groups of x / 256 convert blocks

typedef __attribute__((ext_vector_type(4))) float f32x4;
typedef __attribute__((ext_vector_type(8))) short short8;

__device__ __forceinline__ unsigned short f2bf(float f) {
    __hip_bfloat16 h = __float2bfloat16(f);
    return *reinterpret_cast<unsigned short*>(&h);
}
__device__ __forceinline__ float bflo(unsigned int u) { return __uint_as_float(u << 16); }
__device__ __forceinline__ float bfhi(unsigned int u) { return __uint_as_float(u & 0xffff0000u); }

// ---- pass 1: radix-partition edges by dst bucket; convert x in parallel ----
// Blocks [0,256): partition 3125 edges each. Blocks [256,512): x fp32->bf16.
__global__ __launch_bounds__(256) void fill_part1(
    const float* __restrict__ x, const int* __restrict__ ei,
    unsigned short* __restrict__ xb, unsigned long long* __restrict__ gstore,
    int* __restrict__ gcursor)
{
    const int t = threadIdx.x, b = blockIdx.x;
    if (b >= NBK) {                      // streaming convert half of the grid
        const float4* x4 = reinterpret_cast<const float4*>(x);
        ushort4* xb4 = reinterpret_cast<ushort4*>(xb);
        const int j0 = (b - NBK) * CONV_PER_BLOCK;
        for (int j = t; j < CONV_PER_BLOCK; j += 256) {
            float4 v = x4[j0 + j];
            ushort4 o;
            o.x = f2bf(v.x); o.y = f2bf(v.y); o.z = f2bf(v.z); o.w = f2bf(v.w);
            xb4[j0 + j] = o;
        }
        return;
    }
    __shared__ unsigned long long eds[EPB];   // 25 KB staged edges
    __shared__ int hist[NBK], base_[NBK], run[NBK];
    hist[t] = 0; run[t] = 0;
    __syncthreads();
    const int e0 = b * EPB;
    for (int i = t; i < EPB; i += 256) {
        unsigned src = (unsigned)ei[e0 + i];
        unsigned dst = (unsigned)ei[E_EDGES + e0 + i];
        unsigned bk = (unsigned)((dst * MAGIC391) >> 32);
        unsigned low = dst - bk * NSLICE;
        eds[i] = ((unsigned long long)((bk << 16) | low) << 32) | src;
        atomicAdd(&hist[bk], 1);          // LDS atomic
    }
    __syncthreads();
    base_[t] = atomicAdd(&gcursor[t], hist[t]);   // 1 global atomic per bucket
    __syncthreads();
    for (int i = t; i < EPB; i += 256) {
        unsigned long long u = eds[i];
        unsigned bk = (unsigned)(u >> 48);
        int p = base_[bk] + atomicAdd(&run[bk], 1);   // LDS atomic
        if (p < BKCAP)                                 // (never trips w.h.p.)
            gstore[bk * BKCAP + p] = u & 0x0000ffffffffffffULL;  // (low,src)
    }
}

// ---- pass 2: per-bucket cnt+slot build in LDS, coalesced writeback ---------
__global__ __launch_bounds__(256) void fill_part2(
    const unsigned long long* __restrict__ gstore, const int* __restrict__ gcursor,
    int* __restrict__ cnt, int* __restrict__ slots)
{
    __shared__ int cnt_l[NSLICE];
    __shared__ int slots_l[NSLICE * CAP];   // 50 KB
    const int t = threadIdx.x, b = blockIdx.x;
    const int base = b * NSLICE;
    for (int i = t; i < NSLICE; i += 256) cnt_l[i] = 0;
    __syncthreads();
    int n = gcursor[b];
    if (n > BKCAP) n = BKCAP;
    const unsigned long long* bs = gstore + b * BKCAP;
    for (int i = t; i < n; i += 256) {
        unsigned long long u = bs[i];               // coalesced 8B reads
        unsigned low = (unsigned)(u >> 32);
        int p = atomicAdd(&cnt_l[low], 1);          // LDS atomic
        if (p < CAP) slots_l[low * CAP + p] = (int)(unsigned)u;
    }
    __syncthreads();
    for (int i = t; i < NSLICE; i += 256) cnt[base + i] = cnt_l[i];
    for (int i = t; i < NSLICE * CAP; i += 256) slots[base * CAP + i] = slots_l[i];
}

// ---- quad-row pull-gather mean into bf16 neigh ------------------------------
// Wave per node. Lane = (subi = lane>>4) neighbor sub-index, (chunk = lane&15)
// 16B feature chunk. One uint4 load = 4 neighbor rows (1KB) per instruction.
__global__ __launch_bounds__(256) void gather_kernel(
    const unsigned short* __restrict__ xb, const int* __restrict__ cnt,
    const int* __restrict__ slots, unsigned short* __restrict__ nb)
{
    int node = (blockIdx.x * blockDim.x + threadIdx.x) >> 6;
    int lane = threadIdx.x & 63;
    if (node >= N_NODES) return;
    int c = cnt[node];
    int cc = c > CAP ? CAP : c;
    int myslot = (lane < cc) ? slots[node * CAP + lane] : 0;  // lanes >= cc hold 0
    const int subi = lane >> 4, chunk = lane & 15;
    float acc[8];
#pragma unroll
    for (int k = 0; k < 8; ++k) acc[k] = 0.f;
    const uint4* x4 = reinterpret_cast<const uint4*>(xb);  // 16 uint4 per row
    for (int i = 0; i < cc; i += 4) {
        int idx = i + subi;                 // <= cc+3 <= 35 < 64: safe shfl index
        int s = __shfl(myslot, idx);        // idx >= cc -> lane holds 0 -> row 0
        uint4 v = x4[s * 16 + chunk];
        if (idx < cc) {
            acc[0] += bflo(v.x); acc[1] += bfhi(v.x);
            acc[2] += bflo(v.y); acc[3] += bfhi(v.y);
            acc[4] += bflo(v.z); acc[5] += bfhi(v.z);
            acc[6] += bflo(v.w); acc[7] += bfhi(v.w);
        }
    }
#pragma unroll
    for (int k = 0; k < 8; ++k) {           // sum across the 4 neighbor groups
        acc[k] += __shfl_xor(acc[k], 16);
        acc[k] += __shfl_xor(acc[k], 32);
    }
    if (subi == 0) {
        float inv = 1.0f / (float)(c > 1 ? c : 1);
        uint4 o;
        o.x = ((unsigned)f2bf(acc[1] * inv) << 16) | f2bf(acc[0] * inv);
        o.y = ((unsigned)f2bf(acc[3] * inv) << 16) | f2bf(acc[2] * inv);
        o.z = ((unsigned)f2bf(acc[5] * inv) << 16) | f2bf(acc[4] * inv);
        o.w = ((unsigned)f2bf(acc[7] * inv) << 16) | f2bf(acc[6] * inv);
        reinterpret_cast<uint4*>(nb)[node * 16 + chunk] = o;
    }
}

// ---- MFMA GEMM (K=256 over [x|neigh]) + bias + ReLU + LayerNorm ------------
// Block = 256 thr = 4 waves; wave owns 64 rows x 128 cols.
// A-frag: A[m=lane&15][k=quad*8+j]; C/D: col=lane&15, row=quad*4+reg.
__global__ __launch_bounds__(256, 2) void fused_mfma(
    const unsigned short* __restrict__ xb, const unsigned short* __restrict__ nb,
    const float* __restrict__ Wself, const float* __restrict__ Wneigh,
    const float* __restrict__ bias, const float* __restrict__ gamma,
    const float* __restrict__ beta, float* __restrict__ out)
{
    __shared__ unsigned short WT[128][WPAD];   // [out_col][kk]; kk<128: Ws, else Wn
    const int t = threadIdx.x;
    const float4* Ws4 = reinterpret_cast<const float4*>(Wself);
    const float4* Wn4 = reinterpret_cast<const float4*>(Wneigh);
    for (int idx = t; idx < 4096; idx += 256) {
        int n = idx >> 5, k4 = (idx & 31) << 2;     // W is [n][k], coalesced read
        float4 a = Ws4[idx];
        float4 b = Wn4[idx];
        ushort4 ua, ub;
        ua.x = f2bf(a.x); ua.y = f2bf(a.y); ua.z = f2bf(a.z); ua.w = f2bf(a.w);
        ub.x = f2bf(b.x); ub.y = f2bf(b.y); ub.z = f2bf(b.z); ub.w = f2bf(b.w);
        *reinterpret_cast<ushort4*>(&WT[n][k4]) = ua;
        *reinterpret_cast<ushort4*>(&WT[n][128 + k4]) = ub;
    }
    __syncthreads();

    const int lane = t & 63, wave = t >> 6;
    const int l16 = lane & 15, quad = lane >> 4;
    float bia[8], gam[8], bet[8];
#pragma unroll
    for (int n = 0; n < 8; ++n) {
        int col = n * 16 + l16;
        bia[n] = bias[col]; gam[n] = gamma[col]; bet[n] = beta[col];
    }

    const int ntiles = (N_NODES + 255) / 256;
    for (int tile = blockIdx.x; tile < ntiles; tile += gridDim.x) {
        const int rowbase = tile * 256 + wave * 64;
        f32x4 acc[4][8];
#pragma unroll
        for (int m = 0; m < 4; ++m)
#pragma unroll
            for (int n = 0; n < 8; ++n) acc[m][n] = (f32x4)0.f;
        int rows[4];
#pragma unroll
        for (int m = 0; m < 4; ++m) {
            int r = rowbase + m * 16 + l16;
            rows[m] = r < N_NODES ? r : N_NODES - 1;   // tail clamp; store guarded
        }
#pragma unroll
        for (int kstep = 0; kstep < 8; ++kstep) {
            const unsigned short* Asrc = (kstep < 4) ? xb : nb;
            const int koff = (kstep & 3) * 32 + quad * 8;
            short8 a[4];
#pragma unroll
            for (int m = 0; m < 4; ++m)
                a[m] = *reinterpret_cast<const short8*>(Asrc + rows[m] * 128 + koff);
#pragma unroll
            for (int n = 0; n < 8; ++n) {
                short8 b = *reinterpret_cast<const short8*>(&WT[n * 16 + l16][kstep * 32 + quad * 8]);
#pragma unroll
                for (int m = 0; m < 4; ++m)
                    acc[m][n] = __builtin_amdgcn_mfma_f32_16x16x32_bf16(a[m], b, acc[m][n], 0, 0, 0);
            }
        }
        // epilogue: bias+ReLU+LN; row R's 128 cols live in the 16 lanes of one quad
#pragma unroll
        for (int m = 0; m < 4; ++m) {
#pragma unroll
            for (int r = 0; r < 4; ++r) {
                float h[8], s = 0.f, q = 0.f;
#pragma unroll
                for (int n = 0; n < 8; ++n) {
                    float v = acc[m][n][r] + bia[n];
                    v = fmaxf(v, 0.f);
                    h[n] = v; s += v; q += v * v;
                }
#pragma unroll
                for (int msk = 1; msk <= 8; msk <<= 1) {
                    s += __shfl_xor(s, msk);
                    q += __shfl_xor(q, msk);
                }
                const float mu = s * (1.f / 128.f);
                const float var = q * (1.f / 128.f) - mu * mu;
                const float rs = rsqrtf(var + LN_EPS);
                const int R = rowbase + m * 16 + quad * 4 + r;
                if (R < N_NODES) {
#pragma unroll
                    for (int n = 0; n < 8; ++n)
                        out[R * 128 + n * 16 + l16] = (h[n] - mu) * rs * gam[n] + bet[n];
                }
            }
        }
    }
}

extern "C" void kernel_launch(void* const* d_in, const int* in_sizes, int n_in,
                              void* d_out, int out_size, void* d_ws, size_t ws_size,
                              hipStream_t stream) {
    const float* x      = (const float*)d_in[0];
    const int*   ei     = (const int*)d_in[1];
    const float* Wself  = (const float*)d_in[2];
    const float* Wneigh = (const float*)d_in[3];
    const float* bias   = (const float*)d_in[4];
    const float* gamma  = (const float*)d_in[5];
    const float* beta   = (const float*)d_in[6];
    float* out = (float*)d_out;

    // ws layout (64.42 MB): nb aliases gstore (dead after pass 2)
    char* ws = (char*)d_ws;
    unsigned short* xb = (unsigned short*)ws;                        // 25,600,000
    int* cnt   = (int*)(ws + 25600000);                              //    400,384
    int* slots = (int*)(ws + 26000384);                              // 12,812,288
    unsigned long long* gstore = (unsigned long long*)(ws + 38812672); // 8,388,608
    unsigned short* nb = (unsigned short*)(ws + 38812672);           // 25,600,000
    int* gcursor = (int*)(ws + 64412672);                            //      1,024

    hipMemsetAsync(gcursor, 0, NBK * sizeof(int), stream);
    fill_part1<<<512, 256, 0, stream>>>(x, ei, xb, gstore, gcursor);
    fill_part2<<<NBK, 256, 0, stream>>>(gstore, gcursor, cnt, slots);
    gather_kernel<<<(N_NODES + 3) / 4, 256, 0, stream>>>(xb, cnt, slots, nb);
    const int ntiles = (N_NODES + 255) / 256;
    fused_mfma<<<ntiles, 256, 0, stream>>>(xb, nb, Wself, Wneigh, bias, gamma, beta, out);
}

// Round 6
// 204.757 us; speedup vs baseline: 2.5046x; 1.0274x over previous
//
#include <hip/hip_runtime.h>
#include <hip/hip_bf16.h>

#define N_NODES 100000
#define E_EDGES 800000
#define LN_EPS 1e-5f
#define WPAD 264           // 256 + 8 bf16 pad -> max 2-way LDS bank aliasing (free)

#define P_BLOCKS 256       // partition blocks
#define EPB 3125           // edges per partition block (800000/256, exact)
#define SLICE 64           // nodes per bucket (power of 2: bk = dst>>6)
#define NBK 1563           // ceil(100000/64); grid of agg2
#define NBK_PAD 1792       // 7*256 (scan convenience)
#define OFFS_STRIDE 1564   // per-block stored starts incl sentinel
#define QCAP 768           // bucket edge capacity (mean 512, sd 23 -> 11 sigma)
#define CONV_PER_BLOCK 12500   // 3.2M float4 groups of x / 256 convert blocks

typedef __attribute__((ext_vector_type(4))) float f32x4;
typedef __attribute__((ext_vector_type(8))) short short8;

__device__ __forceinline__ unsigned short f2bf(float f) {
    __hip_bfloat16 h = __float2bfloat16(f);
    return *reinterpret_cast<unsigned short*>(&h);
}
__device__ __forceinline__ float bflo(unsigned int u) { return __uint_as_float(u << 16); }
__device__ __forceinline__ float bfhi(unsigned int u) { return __uint_as_float(u & 0xffff0000u); }

// ---- pass 1: LDS counting-sort of edges by bucket, coalesced writeback ------
// Blocks [0,256): sort 3125 edges each, write block-major sorted records +
// per-bucket start offsets. Blocks [256,512): x fp32->bf16 streaming convert.
// No global atomics anywhere.
__global__ __launch_bounds__(256) void fill_part1(
    const float* __restrict__ x, const int* __restrict__ ei,
    unsigned short* __restrict__ xb, unsigned int* __restrict__ gstore,
    unsigned short* __restrict__ offs)
{
    const int t = threadIdx.x, b = blockIdx.x;
    if (b >= P_BLOCKS) {                 // streaming convert half of the grid
        const float4* x4 = reinterpret_cast<const float4*>(x);
        ushort4* xb4 = reinterpret_cast<ushort4*>(xb);
        const int j0 = (b - P_BLOCKS) * CONV_PER_BLOCK;
        for (int j = t; j < CONV_PER_BLOCK; j += 256) {
            float4 v = x4[j0 + j];
            ushort4 o;
            o.x = f2bf(v.x); o.y = f2bf(v.y); o.z = f2bf(v.z); o.w = f2bf(v.w);
            xb4[j0 + j] = o;
        }
        return;
    }
    __shared__ unsigned long long eds[EPB];   // 25,000 B staged edges
    __shared__ unsigned int sorted_l[EPB];    // 12,500 B sorted u32 records
    __shared__ int hist[NBK_PAD];             // 7,168 B (reused as run counters)
    __shared__ int starts[NBK_PAD + 1];       // 7,172 B
    __shared__ int partial[256];
    for (int i = t; i < NBK_PAD; i += 256) hist[i] = 0;
    __syncthreads();
    const int e0 = b * EPB;
    for (int i = t; i < EPB; i += 256) {
        unsigned src = (unsigned)ei[e0 + i];
        unsigned dst = (unsigned)ei[E_EDGES + e0 + i];
        unsigned bk = dst >> 6;
        eds[i] = ((unsigned long long)bk << 32) | (src << 6) | (dst & 63u);
        atomicAdd(&hist[bk], 1);              // LDS atomic
    }
    __syncthreads();
    // exclusive scan of hist: thread t owns buckets [7t, 7t+7)
    int h[7], s = 0;
#pragma unroll
    for (int k = 0; k < 7; ++k) { h[k] = hist[t * 7 + k]; s += h[k]; }
    partial[t] = s;
    __syncthreads();
    for (int off = 1; off < 256; off <<= 1) {   // Hillis-Steele over 256
        int v = (t >= off) ? partial[t - off] : 0;
        __syncthreads();
        partial[t] += v;
        __syncthreads();
    }
    int run = partial[t] - s;                   // exclusive prefix
#pragma unroll
    for (int k = 0; k < 7; ++k) { starts[t * 7 + k] = run; run += h[k]; }
    if (t == 255) starts[NBK_PAD] = run;        // == EPB
    __syncthreads();
    for (int i = t; i < NBK_PAD; i += 256) hist[i] = 0;   // reuse as run ctr
    __syncthreads();
    for (int i = t; i < EPB; i += 256) {        // scatter into sorted order
        unsigned long long u = eds[i];
        unsigned bk = (unsigned)(u >> 32);
        int p = starts[bk] + atomicAdd(&hist[bk], 1);
        sorted_l[p] = (unsigned int)u;
    }
    __syncthreads();
    for (int i = t; i < EPB; i += 256)          // coalesced writeback
        gstore[b * EPB + i] = sorted_l[i];
    for (int i = t; i < OFFS_STRIDE; i += 256)
        offs[b * OFFS_STRIDE + i] = (unsigned short)starts[i];
}

// ---- pass 2: per-bucket LDS counting-sort -> quad-row register gather ------
// Block b owns nodes [64b, 64b+64). Reads its ~512 records from the 256
// part-1 runs, sorts by node in LDS (~3.8 KB total -> high occupancy), then
// gathers x rows with 16B/lane quad-row loads, register accumulation, exact
// degree (no CAP). Writes nb bf16 coalesced.
__global__ __launch_bounds__(256) void agg2(
    const unsigned int* __restrict__ gstore, const unsigned short* __restrict__ offs,
    const unsigned short* __restrict__ xb, unsigned short* __restrict__ nb)
{
    __shared__ unsigned int sortedq[QCAP];   // 3,072 B
    __shared__ int cnt_l[SLICE];
    __shared__ int run_l[SLICE];
    __shared__ int qs_l[SLICE + 1];
    const int t = threadIdx.x, b = blockIdx.x;
    if (t < SLICE) { cnt_l[t] = 0; run_l[t] = 0; }
    __syncthreads();
    const int s0 = offs[t * OFFS_STRIDE + b];
    const int s1 = offs[t * OFFS_STRIDE + b + 1];
    const unsigned int* myrun = gstore + t * EPB;
    for (int j = s0; j < s1; ++j)             // pass A: histogram by node
        atomicAdd(&cnt_l[myrun[j] & 63u], 1);
    __syncthreads();
    if (t < SLICE) {                          // wave-0 shfl scan of 64 counts
        int inc = cnt_l[t];
        for (int off = 1; off < 64; off <<= 1) {
            int u = __shfl_up(inc, off);
            if (t >= off) inc += u;
        }
        qs_l[t + 1] = inc;
        if (t == 0) qs_l[0] = 0;
    }
    __syncthreads();
    for (int j = s0; j < s1; ++j) {           // pass B: scatter (L1-hot reread)
        unsigned rec = myrun[j];
        int p = qs_l[rec & 63u] + atomicAdd(&run_l[rec & 63u], 1);
        if (p < QCAP) sortedq[p] = rec;
    }
    __syncthreads();
    // quad-row gather: wave owns 16 nodes; lane = subi(4 edges) x chunk(16B)
    const int wave = t >> 6, lane = t & 63;
    const int subi = lane >> 4, chunk = lane & 15;
    const uint4* x4 = reinterpret_cast<const uint4*>(xb);   // 16 uint4 per row
    for (int ln = wave * 16; ln < wave * 16 + 16; ++ln) {
        const int qb = qs_l[ln], cc = qs_l[ln + 1] - qb;
        float acc[8];
#pragma unroll
        for (int k = 0; k < 8; ++k) acc[k] = 0.f;
        for (int i = 0; i < cc; i += 4) {
            int idx = i + subi;
            if (idx < cc) {                   // quad-uniform branch
                unsigned rec = sortedq[qb + idx];
                uint4 v = x4[(rec >> 6) * 16 + chunk];
                acc[0] += bflo(v.x); acc[1] += bfhi(v.x);
                acc[2] += bflo(v.y); acc[3] += bfhi(v.y);
                acc[4] += bflo(v.z); acc[5] += bfhi(v.z);
                acc[6] += bflo(v.w); acc[7] += bfhi(v.w);
            }
        }
#pragma unroll
        for (int k = 0; k < 8; ++k) {         // sum the 4 neighbor groups
            acc[k] += __shfl_xor(acc[k], 16);
            acc[k] += __shfl_xor(acc[k], 32);
        }
        const int node = b * SLICE + ln;
        if (subi == 0 && node < N_NODES) {
            float inv = 1.0f / (float)(cc > 1 ? cc : 1);
            uint4 o;
            o.x = ((unsigned)f2bf(acc[1] * inv) << 16) | f2bf(acc[0] * inv);
            o.y = ((unsigned)f2bf(acc[3] * inv) << 16) | f2bf(acc[2] * inv);
            o.z = ((unsigned)f2bf(acc[5] * inv) << 16) | f2bf(acc[4] * inv);
            o.w = ((unsigned)f2bf(acc[7] * inv) << 16) | f2bf(acc[6] * inv);
            reinterpret_cast<uint4*>(nb)[node * 16 + chunk] = o;
        }
    }
}

// ---- MFMA GEMM (K=256 over [x|neigh]) + bias + ReLU + LayerNorm ------------
// Block = 256 thr = 4 waves; wave owns 64 rows x 128 cols.
// A-frag: A[m=lane&15][k=quad*8+j]; C/D: col=lane&15, row=quad*4+reg.
__global__ __launch_bounds__(256, 2) void fused_mfma(
    const unsigned short* __restrict__ xb, const unsigned short* __restrict__ nb,
    const float* __restrict__ Wself, const float* __restrict__ Wneigh,
    const float* __restrict__ bias, const float* __restrict__ gamma,
    const float* __restrict__ beta, float* __restrict__ out)
{
    __shared__ unsigned short WT[128][WPAD];   // [out_col][kk]; kk<128: Ws, else Wn
    const int t = threadIdx.x;
    const float4* Ws4 = reinterpret_cast<const float4*>(Wself);
    const float4* Wn4 = reinterpret_cast<const float4*>(Wneigh);
    for (int idx = t; idx < 4096; idx += 256) {
        int n = idx >> 5, k4 = (idx & 31) << 2;     // W is [n][k], coalesced read
        float4 a = Ws4[idx];
        float4 b = Wn4[idx];
        ushort4 ua, ub;
        ua.x = f2bf(a.x); ua.y = f2bf(a.y); ua.z = f2bf(a.z); ua.w = f2bf(a.w);
        ub.x = f2bf(b.x); ub.y = f2bf(b.y); ub.z = f2bf(b.z); ub.w = f2bf(b.w);
        *reinterpret_cast<ushort4*>(&WT[n][k4]) = ua;
        *reinterpret_cast<ushort4*>(&WT[n][128 + k4]) = ub;
    }
    __syncthreads();

    const int lane = t & 63, wave = t >> 6;
    const int l16 = lane & 15, quad = lane >> 4;
    float bia[8], gam[8], bet[8];
#pragma unroll
    for (int n = 0; n < 8; ++n) {
        int col = n * 16 + l16;
        bia[n] = bias[col]; gam[n] = gamma[col]; bet[n] = beta[col];
    }

    const int ntiles = (N_NODES + 255) / 256;
    for (int tile = blockIdx.x; tile < ntiles; tile += gridDim.x) {
        const int rowbase = tile * 256 + wave * 64;
        f32x4 acc[4][8];
#pragma unroll
        for (int m = 0; m < 4; ++m)
#pragma unroll
            for (int n = 0; n < 8; ++n) acc[m][n] = (f32x4)0.f;
        int rows[4];
#pragma unroll
        for (int m = 0; m < 4; ++m) {
            int r = rowbase + m * 16 + l16;
            rows[m] = r < N_NODES ? r : N_NODES - 1;   // tail clamp; store guarded
        }
#pragma unroll
        for (int kstep = 0; kstep < 8; ++kstep) {
            const unsigned short* Asrc = (kstep < 4) ? xb : nb;
            const int koff = (kstep & 3) * 32 + quad * 8;
            short8 a[4];
#pragma unroll
            for (int m = 0; m < 4; ++m)
                a[m] = *reinterpret_cast<const short8*>(Asrc + rows[m] * 128 + koff);
#pragma unroll
            for (int n = 0; n < 8; ++n) {
                short8 b = *reinterpret_cast<const short8*>(&WT[n * 16 + l16][kstep * 32 + quad * 8]);
#pragma unroll
                for (int m = 0; m < 4; ++m)
                    acc[m][n] = __builtin_amdgcn_mfma_f32_16x16x32_bf16(a[m], b, acc[m][n], 0, 0, 0);
            }
        }
        // epilogue: bias+ReLU+LN; row R's 128 cols live in the 16 lanes of one quad
#pragma unroll
        for (int m = 0; m < 4; ++m) {
#pragma unroll
            for (int r = 0; r < 4; ++r) {
                float h[8], s = 0.f, q = 0.f;
#pragma unroll
                for (int n = 0; n < 8; ++n) {
                    float v = acc[m][n][r] + bia[n];
                    v = fmaxf(v, 0.f);
                    h[n] = v; s += v; q += v * v;
                }
#pragma unroll
                for (int msk = 1; msk <= 8; msk <<= 1) {
                    s += __shfl_xor(s, msk);
                    q += __shfl_xor(q, msk);
                }
                const float mu = s * (1.f / 128.f);
                const float var = q * (1.f / 128.f) - mu * mu;
                const float rs = rsqrtf(var + LN_EPS);
                const int R = rowbase + m * 16 + quad * 4 + r;
                if (R < N_NODES) {
#pragma unroll
                    for (int n = 0; n < 8; ++n)
                        out[R * 128 + n * 16 + l16] = (h[n] - mu) * rs * gam[n] + bet[n];
                }
            }
        }
    }
}

extern "C" void kernel_launch(void* const* d_in, const int* in_sizes, int n_in,
                              void* d_out, int out_size, void* d_ws, size_t ws_size,
                              hipStream_t stream) {
    const float* x      = (const float*)d_in[0];
    const int*   ei     = (const int*)d_in[1];
    const float* Wself  = (const float*)d_in[2];
    const float* Wneigh = (const float*)d_in[3];
    const float* bias   = (const float*)d_in[4];
    const float* gamma  = (const float*)d_in[5];
    const float* beta   = (const float*)d_in[6];
    float* out = (float*)d_out;

    // ws layout (55.2 MB used)
    char* ws = (char*)d_ws;
    unsigned short* xb = (unsigned short*)ws;                       // 25,600,000
    unsigned short* nb = (unsigned short*)(ws + 25600000);          // 25,600,000
    unsigned int* gstore = (unsigned int*)(ws + 51200000);          //  3,200,000
    unsigned short* offs = (unsigned short*)(ws + 54400000);        //    800,768

    fill_part1<<<512, 256, 0, stream>>>(x, ei, xb, gstore, offs);
    agg2<<<NBK, 256, 0, stream>>>(gstore, offs, xb, nb);
    const int ntiles = (N_NODES + 255) / 256;
    fused_mfma<<<ntiles, 256, 0, stream>>>(xb, nb, Wself, Wneigh, bias, gamma, beta, out);
}